// Round 4
// baseline (1348.562 us; speedup 1.0000x reference)
//
#include <hip/hip_runtime.h>

#define BATCH 64
#define TT    1024
#define INC   16
#define NN    512
#define RNK   16
#define OUTC  8

// a = DT/TAU = 0.1
#define A_COEF 0.1f

__device__ __forceinline__ float fast_tanh(float x) {
    // tanh(x) = 1 - 2/(exp(2x)+1); safe at +/-inf
    float e = __expf(2.0f * x);
    return 1.0f - __fdividef(2.0f, e + 1.0f);
}

// ---- DPP cross-lane mov (VALU pipe, ~4-8 cyc) ----
// ctrl: quad_perm[1,0,3,2]=0xB1 (xor1), quad_perm[2,3,0,1]=0x4E (xor2),
//       row_half_mirror=0x141 (xor7), row_ror:8=0x128 (xor8 within 16)
#define DPP_XOR1 0xB1
#define DPP_XOR2 0x4E
#define DPP_XOR7 0x141
#define DPP_XOR8 0x128
template<int CTRL>
__device__ __forceinline__ float dpp_mov(float x) {
    return __int_as_float(
        __builtin_amdgcn_update_dpp(0, __float_as_int(x), CTRL, 0xF, 0xF, true));
}

// ds_swizzle xor16 (BitMode: offset = (xor_mask<<10) | 0x1F)
__device__ __forceinline__ float swz_xor16(float x) {
    return __int_as_float(__builtin_amdgcn_ds_swizzle(__float_as_int(x), 0x401F));
}
// xor32 via ds_bpermute (BitMode is 32-lane only); xaddr = ((p^32)&63)<<2
__device__ __forceinline__ float bperm_x32(int xaddr, float x) {
    return __int_as_float(__builtin_amdgcn_ds_bpermute(xaddr, __float_as_int(x)));
}

// ---- packed dual-FP32 FMA (VOP3P; exact f32 fma semantics) ----
// d = a * broadcast(b.lo or b.hi) + c
__device__ __forceinline__ float2 pk_fma_blo(float2 a, float2 b, float2 c) {
    float2 d;
    asm("v_pk_fma_f32 %0, %1, %2, %3 op_sel_hi:[1,0,1]"
        : "=v"(d) : "v"(a), "v"(b), "v"(c));
    return d;
}
__device__ __forceinline__ float2 pk_fma_bhi(float2 a, float2 b, float2 c) {
    float2 d;
    asm("v_pk_fma_f32 %0, %1, %2, %3 op_sel:[0,1,0] op_sel_hi:[1,1,1]"
        : "=v"(d) : "v"(a), "v"(b), "v"(c));
    return d;
}

// ---------------------------------------------------------------------------
// Pre-pass: Inp[b,t,n] = sum_i x[b,t,i] * In_w[n,i]. Memory-bound (~128 MB
// write) on all 256 CUs; removes the input projection from the scan chain.
// ---------------------------------------------------------------------------
__global__ __launch_bounds__(256) void inp_kernel(
    const float* __restrict__ x,     // [B,T,INC]
    const float* __restrict__ In_w,  // [N,INC]
    float* __restrict__ Inp)         // [B,T,N]
{
    const int wv = (blockIdx.x << 2) | (threadIdx.x >> 6);
    const int p  = threadIdx.x & 63;
    const int NW = gridDim.x << 2;

    float4 W4[8][4];
    #pragma unroll
    for (int k = 0; k < 8; ++k) {
        const float4* wr = (const float4*)&In_w[(p + 64 * k) * INC];
        W4[k][0] = wr[0]; W4[k][1] = wr[1]; W4[k][2] = wr[2]; W4[k][3] = wr[3];
    }

    const int ROWS = BATCH * TT;
    for (int r = wv; r < ROWS; r += NW) {
        const float4* xr = (const float4*)(x + (size_t)r * INC);
        float4 x0 = xr[0], x1 = xr[1], x2 = xr[2], x3 = xr[3];
        #pragma unroll
        for (int k = 0; k < 8; ++k) {
            float a = W4[k][0].x * x0.x;
            float b = W4[k][0].y * x0.y;
            float c = W4[k][0].z * x0.z;
            float d = W4[k][0].w * x0.w;
            a = fmaf(W4[k][1].x, x1.x, a);
            b = fmaf(W4[k][1].y, x1.y, b);
            c = fmaf(W4[k][1].z, x1.z, c);
            d = fmaf(W4[k][1].w, x1.w, d);
            a = fmaf(W4[k][2].x, x2.x, a);
            b = fmaf(W4[k][2].y, x2.y, b);
            c = fmaf(W4[k][2].z, x2.z, c);
            d = fmaf(W4[k][2].w, x2.w, d);
            a = fmaf(W4[k][3].x, x3.x, a);
            b = fmaf(W4[k][3].y, x3.y, b);
            c = fmaf(W4[k][3].z, x3.z, c);
            d = fmaf(W4[k][3].w, x3.w, d);
            Inp[(size_t)r * NN + p + 64 * k] = (a + b) + (c + d);
        }
    }
}

// Out-projection fragment: opart[o] for 8 o's from this lane's 8 phi values,
// then reduce-scatter over 64 lanes. Returns full sum (valid in all lanes);
// lane p<8 stores o = tau(p). Slot meaning tau_p(s) = s ^ rho3(p) is baked
// into the Opk weight layout.
__device__ __forceinline__ float out_project(const float2 phipk[4],
                                             const float2 Opk[8][4], int xaddr) {
    float2 opk[4];
    #pragma unroll
    for (int u = 0; u < 4; ++u) opk[u] = make_float2(0.f, 0.f);
    #pragma unroll
    for (int j2 = 0; j2 < 4; ++j2)
        #pragma unroll
        for (int u = 0; u < 4; ++u) {
            opk[u] = pk_fma_blo(Opk[2 * j2][u],     phipk[j2], opk[u]);
            opk[u] = pk_fma_bhi(Opk[2 * j2 + 1][u], phipk[j2], opk[u]);
        }
    // reduce-scatter: slots 8 -> 4 -> 2 -> 1, then pure adds over xor8/16/32
    #pragma unroll
    for (int u = 0; u < 4; ++u) opk[u].x += dpp_mov<DPP_XOR1>(opk[u].y);
    opk[0].x += dpp_mov<DPP_XOR2>(opk[2].x);
    opk[1].x += dpp_mov<DPP_XOR2>(opk[3].x);
    opk[0].x += dpp_mov<DPP_XOR7>(opk[1].x);
    float O0 = opk[0].x;
    O0 += dpp_mov<DPP_XOR8>(O0);
    O0 += swz_xor16(O0);
    O0 += bperm_x32(xaddr, O0);
    return O0;
}

// ---------------------------------------------------------------------------
// Scan: ONE WAVE PER BATCH (64 blocks x 64 threads). 8 states per lane; V, U,
// Out_w entirely in registers (~400 VGPR, fine at 1 wave/SIMD). No LDS, no
// barriers. low[r] (r=16) computed via register butterfly reduce-scatter
// (DPP xor1/xor2/xor7/xor8 + swizzle xor16 + bpermute xor32) + DPP all-gather.
// The butterfly's lane<->slot permutation sigma_p(s)=s^rho(p) is baked into
// the V/U/Out weight load addresses (zero runtime cost). Out-projection fused
// (writes out[t-1] from phi_t). Inp precomputed, prefetched one step ahead.
// ---------------------------------------------------------------------------
__global__ __launch_bounds__(64, 1) void scan_kernel(
    const float* __restrict__ Inp,    // [B,T,N]
    const float* __restrict__ V_w,    // [R,N]
    const float* __restrict__ U_w,    // [N,R]
    const float* __restrict__ Out_w,  // [OUTC,N]
    const float* __restrict__ h0,     // [N]
    float* __restrict__ hidden,       // [B,T,N]
    float* __restrict__ out)          // [B,T,OUTC]
{
    const int p  = threadIdx.x;   // 0..63
    const int b  = blockIdx.x;
    const int n0 = p * 8;         // this lane's states: n0..n0+7
    const int xaddr = ((p ^ 32) & 63) << 2;

    // stage masks {1,2,7,8}: rho bits chosen so stage mask m flips exactly
    // its own slot bit (see derivation: rho3=b0^b2, rho2=b1^b2, rho1=b2, rho0=b3)
    const int b0 = p & 1, b1 = (p >> 1) & 1, b2 = (p >> 2) & 1, b3 = (p >> 3) & 1;
    const int rho4 = ((b0 ^ b2) << 3) | ((b1 ^ b2) << 2) | (b2 << 1) | b3;
    const int rho3 = ((b0 ^ b2) << 2) | ((b1 ^ b2) << 1) | b2;

    // ---- V: Vpk[j][q] = (V[q^rho4][n0+j], V[(q^rho4)^8][n0+j]) ----
    float2 Vpk[8][8];
    #pragma unroll
    for (int q = 0; q < 8; ++q) {
        const int rlo = q ^ rho4, rhi = rlo ^ 8;
        const float4* vl = (const float4*)&V_w[rlo * NN + n0];
        const float4* vh = (const float4*)&V_w[rhi * NN + n0];
        float4 a0 = vl[0], a1 = vl[1], c0 = vh[0], c1 = vh[1];
        Vpk[0][q] = make_float2(a0.x, c0.x);
        Vpk[1][q] = make_float2(a0.y, c0.y);
        Vpk[2][q] = make_float2(a0.z, c0.z);
        Vpk[3][q] = make_float2(a0.w, c0.w);
        Vpk[4][q] = make_float2(a1.x, c1.x);
        Vpk[5][q] = make_float2(a1.y, c1.y);
        Vpk[6][q] = make_float2(a1.z, c1.z);
        Vpk[7][q] = make_float2(a1.w, c1.w);
    }

    // ---- U: Upk[m][s] = (U[n0+2m][s^rho4], U[n0+2m+1][s^rho4]) ----
    float2 Upk[4][16];
    #pragma unroll
    for (int m = 0; m < 4; ++m)
        #pragma unroll
        for (int s = 0; s < 16; ++s)
            Upk[m][s] = make_float2(U_w[(n0 + 2 * m) * RNK + (s ^ rho4)],
                                    U_w[(n0 + 2 * m + 1) * RNK + (s ^ rho4)]);

    // ---- Out_w: Opk[j][u] = (Ow[u^rho3][n0+j], Ow[(u^rho3)^4][n0+j]) ----
    float2 Opk[8][4];
    #pragma unroll
    for (int j = 0; j < 8; ++j)
        #pragma unroll
        for (int u = 0; u < 4; ++u) {
            const int olo = u ^ rho3, ohi = olo ^ 4;
            Opk[j][u] = make_float2(Out_w[olo * NN + n0 + j],
                                    Out_w[ohi * NN + n0 + j]);
        }

    // ---- state ----
    float2 hpk[4];
    #pragma unroll
    for (int m = 0; m < 4; ++m) hpk[m] = *(const float2*)&h0[n0 + 2 * m];

    const float* iA = Inp + (size_t)b * TT * NN;
    float* hb = hidden + (size_t)b * TT * NN;
    float* ob = out + (size_t)b * TT * OUTC;

    float4 c0 = *(const float4*)(iA + n0);       // Inp t=0
    float4 c1 = *(const float4*)(iA + n0 + 4);

    for (int t = 0; t < TT; ++t) {
        // phi = tanh(h)   (8 independent)
        float2 phipk[4];
        #pragma unroll
        for (int m = 0; m < 4; ++m)
            phipk[m] = make_float2(fast_tanh(hpk[m].x), fast_tanh(hpk[m].y));

        // prefetch Inp t+1 (off-chain; consumed next iteration)
        const int tn = (t + 1 < TT) ? t + 1 : t;
        float4 nx0 = *(const float4*)(iA + (size_t)tn * NN + n0);
        float4 nx1 = *(const float4*)(iA + (size_t)tn * NN + n0 + 4);

        // ---- V MACs: P[s] = sum_j V[sigma(s)][n_j] * phi[n_j] ----
        float2 Ppk[8];   // Ppk[q] = (P[q], P[q+8])
        #pragma unroll
        for (int q = 0; q < 8; ++q) Ppk[q] = make_float2(0.f, 0.f);
        #pragma unroll
        for (int j2 = 0; j2 < 4; ++j2)
            #pragma unroll
            for (int q = 0; q < 8; ++q) {
                Ppk[q] = pk_fma_blo(Vpk[2 * j2][q],     phipk[j2], Ppk[q]);
                Ppk[q] = pk_fma_bhi(Vpk[2 * j2 + 1][q], phipk[j2], Ppk[q]);
            }

        // out-projection for this phi (= tanh(hidden[t-1])) -> out[t-1]
        float O0 = out_project(phipk, Opk, xaddr);

        // ---- reduce-scatter P: 16 -> 8 -> 4 -> 2 -> 1 slots ----
        #pragma unroll
        for (int q = 0; q < 8; ++q) Ppk[q].x += dpp_mov<DPP_XOR1>(Ppk[q].y);
        #pragma unroll
        for (int s = 0; s < 4; ++s) Ppk[s].x += dpp_mov<DPP_XOR2>(Ppk[s + 4].x);
        Ppk[0].x += dpp_mov<DPP_XOR7>(Ppk[2].x);
        Ppk[1].x += dpp_mov<DPP_XOR7>(Ppk[3].x);
        Ppk[0].x += dpp_mov<DPP_XOR8>(Ppk[1].x);
        float L = Ppk[0].x;
        L += swz_xor16(L);
        L += bperm_x32(xaddr, L);     // L = low[rho4], fully reduced

        // ---- all-gather (pure DPP): G[s] = low[s ^ rho4] ----
        float g0 = L;
        float g1 = dpp_mov<DPP_XOR8>(g0);
        float g2 = dpp_mov<DPP_XOR7>(g0);
        float g3 = dpp_mov<DPP_XOR7>(g1);
        float g4 = dpp_mov<DPP_XOR2>(g0);
        float g5 = dpp_mov<DPP_XOR2>(g1);
        float g6 = dpp_mov<DPP_XOR2>(g2);
        float g7 = dpp_mov<DPP_XOR2>(g3);
        float2 Gp[8];
        Gp[0] = make_float2(g0, g1);
        Gp[1] = make_float2(g2, g3);
        Gp[2] = make_float2(g4, g5);
        Gp[3] = make_float2(g6, g7);
        Gp[4] = make_float2(dpp_mov<DPP_XOR1>(g0), dpp_mov<DPP_XOR1>(g1));
        Gp[5] = make_float2(dpp_mov<DPP_XOR1>(g2), dpp_mov<DPP_XOR1>(g3));
        Gp[6] = make_float2(dpp_mov<DPP_XOR1>(g4), dpp_mov<DPP_XOR1>(g5));
        Gp[7] = make_float2(dpp_mov<DPP_XOR1>(g6), dpp_mov<DPP_XOR1>(g7));

        // ---- U MACs: rec[n] = Inp[n] + sum_s U[n][sigma(s)] * G[s] ----
        float2 recpk[4];
        recpk[0] = make_float2(c0.x, c0.y);
        recpk[1] = make_float2(c0.z, c0.w);
        recpk[2] = make_float2(c1.x, c1.y);
        recpk[3] = make_float2(c1.z, c1.w);
        #pragma unroll
        for (int m = 0; m < 4; ++m)
            #pragma unroll
            for (int u = 0; u < 8; ++u) {
                recpk[m] = pk_fma_blo(Upk[m][2 * u],     Gp[u], recpk[m]);
                recpk[m] = pk_fma_bhi(Upk[m][2 * u + 1], Gp[u], recpk[m]);
            }

        // ---- h update + store ----
        float2* hrow = (float2*)(hb + (size_t)t * NN + n0);
        #pragma unroll
        for (int m = 0; m < 4; ++m) {
            hpk[m].x = fmaf(A_COEF, recpk[m].x - hpk[m].x, hpk[m].x);
            hpk[m].y = fmaf(A_COEF, recpk[m].y - hpk[m].y, hpk[m].y);
            hrow[m] = hpk[m];    // fire-and-forget
        }

        // out[t-1] store (8 lanes, one float each)
        if ((t > 0) && (p < 8)) ob[(size_t)(t - 1) * OUTC + rho3] = O0;

        c0 = nx0; c1 = nx1;
    }

    // epilogue: out[TT-1] from tanh(h_final)
    {
        float2 phipk[4];
        #pragma unroll
        for (int m = 0; m < 4; ++m)
            phipk[m] = make_float2(fast_tanh(hpk[m].x), fast_tanh(hpk[m].y));
        float O0 = out_project(phipk, Opk, xaddr);
        if (p < 8) ob[(size_t)(TT - 1) * OUTC + rho3] = O0;
    }
}

extern "C" void kernel_launch(void* const* d_in, const int* in_sizes, int n_in,
                              void* d_out, int out_size, void* d_ws, size_t ws_size,
                              hipStream_t stream) {
    const float* x    = (const float*)d_in[0];  // [64,1024,16]
    const float* In_w = (const float*)d_in[1];  // [512,16]
    const float* V_w  = (const float*)d_in[2];  // [16,512]
    const float* U_w  = (const float*)d_in[3];  // [512,16]
    const float* Ow   = (const float*)d_in[4];  // [8,512]
    const float* h0   = (const float*)d_in[5];  // [512]

    float* hidden = (float*)d_out;                         // [64,1024,512]
    float* out    = hidden + (size_t)BATCH * TT * NN;      // [64,1024,8]
    float* Inp    = (float*)d_ws;                          // [64,1024,512]

    // 1) input projection (memory-bound)
    inp_kernel<<<1024, 256, 0, stream>>>(x, In_w, Inp);
    // 2) recurrent scan + fused out-projection: one wave per batch
    scan_kernel<<<BATCH, 64, 0, stream>>>(Inp, V_w, U_w, Ow, h0, hidden, out);
}

// Round 6
// 726.639 us; speedup vs baseline: 1.8559x; 1.8559x over previous
//
#include <hip/hip_runtime.h>

#define BATCH 64
#define TT    1024
#define INC   16
#define NN    512
#define RNK   16
#define OUTC  8

// a = DT/TAU = 0.1
#define A_COEF 0.1f

__device__ __forceinline__ float fast_tanh(float x) {
    // tanh(x) = 1 - 2/(exp(2x)+1); safe at +/-inf
    float e = __expf(2.0f * x);
    return 1.0f - __fdividef(2.0f, e + 1.0f);
}

// Barrier with LDS ordering only (does NOT drain vmcnt: global stores/loads
// in flight are never ordered by this barrier).
__device__ __forceinline__ void lgkm_barrier() {
    asm volatile("s_waitcnt lgkmcnt(0)\n\ts_barrier" ::: "memory");
}

// ---- DPP cross-lane ops (VALU pipe) ----
// quad_perm[1,0,3,2]=0xB1 (xor1), quad_perm[2,3,0,1]=0x4E (xor2),
// row_half_mirror=0x141 (xor7 within 16-row), row_ror:8=0x128 (xor8 within 16-row)
#define DPP_XOR1 0xB1
#define DPP_XOR2 0x4E
#define DPP_XOR7 0x141
#define DPP_XOR8 0x128
template<int CTRL>
__device__ __forceinline__ float dpp_mov(float x) {
    return __int_as_float(
        __builtin_amdgcn_update_dpp(0, __float_as_int(x), CTRL, 0xF, 0xF, true));
}

// ---- packed dual-FP32 FMA (VOP3P; exact f32 fma semantics) ----
__device__ __forceinline__ float2 pk_fma_blo(float2 a, float2 b, float2 c) {
    // d.lo = a.lo*b.lo + c.lo ; d.hi = a.hi*b.lo + c.hi   (broadcast b.lo)
    float2 d;
    asm("v_pk_fma_f32 %0, %1, %2, %3 op_sel_hi:[1,0,1]"
        : "=v"(d) : "v"(a), "v"(b), "v"(c));
    return d;
}
__device__ __forceinline__ float2 pk_fma_bhi(float2 a, float2 b, float2 c) {
    // broadcast b.hi
    float2 d;
    asm("v_pk_fma_f32 %0, %1, %2, %3 op_sel:[0,1,0] op_sel_hi:[1,1,1]"
        : "=v"(d) : "v"(a), "v"(b), "v"(c));
    return d;
}

// ---------------------------------------------------------------------------
// Pre-pass: Inp[b,t,n] = sum_i x[b,t,i] * In_w[n,i]. Memory-bound (~128 MB
// write) on all 256 CUs; removes the input projection from the scan chain.
// (verified R3/R4)
// ---------------------------------------------------------------------------
__global__ __launch_bounds__(256) void inp_kernel(
    const float* __restrict__ x,     // [B,T,INC]
    const float* __restrict__ In_w,  // [N,INC]
    float* __restrict__ Inp)         // [B,T,N]
{
    const int wv = (blockIdx.x << 2) | (threadIdx.x >> 6);
    const int p  = threadIdx.x & 63;
    const int NW = gridDim.x << 2;

    float4 W4[8][4];
    #pragma unroll
    for (int k = 0; k < 8; ++k) {
        const float4* wr = (const float4*)&In_w[(p + 64 * k) * INC];
        W4[k][0] = wr[0]; W4[k][1] = wr[1]; W4[k][2] = wr[2]; W4[k][3] = wr[3];
    }

    const int ROWS = BATCH * TT;
    for (int r = wv; r < ROWS; r += NW) {
        const float4* xr = (const float4*)(x + (size_t)r * INC);
        float4 x0 = xr[0], x1 = xr[1], x2 = xr[2], x3 = xr[3];
        #pragma unroll
        for (int k = 0; k < 8; ++k) {
            float a = W4[k][0].x * x0.x;
            float b = W4[k][0].y * x0.y;
            float c = W4[k][0].z * x0.z;
            float d = W4[k][0].w * x0.w;
            a = fmaf(W4[k][1].x, x1.x, a);
            b = fmaf(W4[k][1].y, x1.y, b);
            c = fmaf(W4[k][1].z, x1.z, c);
            d = fmaf(W4[k][1].w, x1.w, d);
            a = fmaf(W4[k][2].x, x2.x, a);
            b = fmaf(W4[k][2].y, x2.y, b);
            c = fmaf(W4[k][2].z, x2.z, c);
            d = fmaf(W4[k][2].w, x2.w, d);
            a = fmaf(W4[k][3].x, x3.x, a);
            b = fmaf(W4[k][3].y, x3.y, b);
            c = fmaf(W4[k][3].z, x3.z, c);
            d = fmaf(W4[k][3].w, x3.w, d);
            Inp[(size_t)r * NN + p + 64 * k] = (a + b) + (c + d);
        }
    }
}

// ---------------------------------------------------------------------------
// Scan: 64 blocks x 256 threads, 1 batch/block, 2 states per lane.
// Each lane's V-partials use only its OWN 2 phi values (R4-verified slot
// scheme, rho4-baked weight layout). Slot reduce via DPP stages {1,2,7,8}
// within each 16-lane row; the 16 row-partials cross waves through ONE
// conflict-free LDS write + ONE barrier (double-buffered -> no WAR barrier)
// + one 4x b128 read; then the R4-verified DPP all-gather feeds the U-MAC.
// Per step: 1 barrier, 1 LDS write, 4 LDS reads.
// R6 fix vs R5: U-MAC loop ran twice over Upk[8..15] (double-count) -> single
// complete pass (each u-iteration consumes Upk[2u..2u+3] with Gp[u],Gp[u+1]).
// ---------------------------------------------------------------------------
__global__ __launch_bounds__(256, 1) void scan_kernel(
    const float* __restrict__ Inp,    // [B,T,N]
    const float* __restrict__ V_w,    // [R,N]
    const float* __restrict__ U_w,    // [N,R]
    const float* __restrict__ h0,     // [N]
    float* __restrict__ hidden)       // [B,T,N]
{
    const int tid = threadIdx.x;     // 0..255
    const int b   = blockIdx.x;
    const int n0  = tid << 1;        // states n0, n0+1
    const int row = tid >> 4;        // 0..15: 4 rows/wave, 16 rows/block
    const int q4  = tid & 15;        // lane within 16-row

    // rho4: slot held by this lane after DPP stages {1,2,7,8} (verified R4)
    const int b0 = q4 & 1, b1 = (q4 >> 1) & 1, b2 = (q4 >> 2) & 1, b3 = (q4 >> 3) & 1;
    const int rho4 = ((b0 ^ b2) << 3) | ((b1 ^ b2) << 2) | (b2 << 1) | b3;

    // row-partials: [buf][slot][row], pitch 20 (write conflict-free, read 2-way)
    __shared__ __align__(16) float lowp[2][16][20];

    // ---- weights in registers (rho4-baked) ----
    // Vpk[j][q] = (V[q^rho4][n0+j], V[(q^rho4)^8][n0+j])
    float2 Vpk[2][8];
    #pragma unroll
    for (int q = 0; q < 8; ++q) {
        const int rlo = q ^ rho4, rhi = rlo ^ 8;
        Vpk[0][q] = make_float2(V_w[rlo * NN + n0],     V_w[rhi * NN + n0]);
        Vpk[1][q] = make_float2(V_w[rlo * NN + n0 + 1], V_w[rhi * NN + n0 + 1]);
    }
    // Upk[s] = (U[n0][s^rho4], U[n0+1][s^rho4])
    float2 Upk[16];
    #pragma unroll
    for (int s = 0; s < 16; ++s)
        Upk[s] = make_float2(U_w[n0 * RNK + (s ^ rho4)],
                             U_w[(n0 + 1) * RNK + (s ^ rho4)]);

    float2 h = *(const float2*)&h0[n0];

    const float* iA = Inp + (size_t)b * TT * NN;
    float* hb = hidden + (size_t)b * TT * NN;

    float2 c = ((const float2*)iA)[tid];   // Inp t=0
    const float2 z2 = make_float2(0.f, 0.f);

    for (int t = 0; t < TT; ++t) {
        float2 phi = make_float2(fast_tanh(h.x), fast_tanh(h.y));

        // prefetch Inp t+1 (off-chain; consumed next iteration)
        const int tn = (t + 1 < TT) ? t + 1 : t;
        float2 nx = ((const float2*)(iA + (size_t)tn * NN))[tid];

        // ---- V partials from own 2 phi: Ppk[q] = (P[q], P[q+8]) ----
        float2 Ppk[8];
        #pragma unroll
        for (int q = 0; q < 8; ++q) {
            Ppk[q] = pk_fma_blo(Vpk[0][q], phi, z2);     // phi.x * V[.][n0]
            Ppk[q] = pk_fma_bhi(Vpk[1][q], phi, Ppk[q]); // phi.y * V[.][n0+1]
        }

        // ---- reduce-scatter within 16-lane row (verified R4) ----
        #pragma unroll
        for (int q = 0; q < 8; ++q) Ppk[q].x += dpp_mov<DPP_XOR1>(Ppk[q].y);
        #pragma unroll
        for (int s = 0; s < 4; ++s) Ppk[s].x += dpp_mov<DPP_XOR2>(Ppk[s + 4].x);
        Ppk[0].x += dpp_mov<DPP_XOR7>(Ppk[2].x);
        Ppk[1].x += dpp_mov<DPP_XOR7>(Ppk[3].x);
        Ppk[0].x += dpp_mov<DPP_XOR8>(Ppk[1].x);
        // lane now holds row-partial of low[rho4]

        lowp[t & 1][rho4][row] = Ppk[0].x;   // conflict-free (2-way max)
        lgkm_barrier();                       // the ONLY barrier per step

        // ---- combine 16 row-partials: 4x b128 (2-way/broadcast) + tree sum ----
        const float4* lp = (const float4*)&lowp[t & 1][rho4][0];
        float4 s0 = lp[0], s1 = lp[1], s2 = lp[2], s3 = lp[3];
        float e0 = (s0.x + s1.x) + (s2.x + s3.x);
        float e1 = (s0.y + s1.y) + (s2.y + s3.y);
        float e2 = (s0.z + s1.z) + (s2.z + s3.z);
        float e3 = (s0.w + s1.w) + (s2.w + s3.w);
        float L = (e0 + e1) + (e2 + e3);     // final low[rho4]

        // ---- all-gather (verified R4): G[s] = low[s ^ rho4] ----
        float g0 = L;
        float g1 = dpp_mov<DPP_XOR8>(g0);
        float g2 = dpp_mov<DPP_XOR7>(g0);
        float g3 = dpp_mov<DPP_XOR7>(g1);
        float g4 = dpp_mov<DPP_XOR2>(g0);
        float g5 = dpp_mov<DPP_XOR2>(g1);
        float g6 = dpp_mov<DPP_XOR2>(g2);
        float g7 = dpp_mov<DPP_XOR2>(g3);
        float2 Gp[8];
        Gp[0] = make_float2(g0, g1);
        Gp[1] = make_float2(g2, g3);
        Gp[2] = make_float2(g4, g5);
        Gp[3] = make_float2(g6, g7);
        Gp[4] = make_float2(dpp_mov<DPP_XOR1>(g0), dpp_mov<DPP_XOR1>(g1));
        Gp[5] = make_float2(dpp_mov<DPP_XOR1>(g2), dpp_mov<DPP_XOR1>(g3));
        Gp[6] = make_float2(dpp_mov<DPP_XOR1>(g4), dpp_mov<DPP_XOR1>(g5));
        Gp[7] = make_float2(dpp_mov<DPP_XOR1>(g6), dpp_mov<DPP_XOR1>(g7));

        // ---- rec = Inp + U . low : ONE complete pass (R6 fix) ----
        // iteration u consumes Upk[2u..2u+3] with Gp[u] (=G[2u],G[2u+1]) and
        // Gp[u+1] (=G[2u+2],G[2u+3]); u=0,2,4,6 covers all 16 slots exactly once.
        float2 recA = c, recB = z2;
        #pragma unroll
        for (int u = 0; u < 8; u += 2) {
            recA = pk_fma_blo(Upk[2 * u],     Gp[u],     recA);
            recA = pk_fma_bhi(Upk[2 * u + 1], Gp[u],     recA);
            recB = pk_fma_blo(Upk[2 * u + 2], Gp[u + 1], recB);
            recB = pk_fma_bhi(Upk[2 * u + 3], Gp[u + 1], recB);
        }
        float2 rec = make_float2(recA.x + recB.x, recA.y + recB.y);

        // ---- h update + store ----
        h.x = fmaf(A_COEF, rec.x - h.x, h.x);
        h.y = fmaf(A_COEF, rec.y - h.y, h.y);
        ((float2*)(hb + (size_t)t * NN))[tid] = h;   // coalesced, fire-and-forget

        c = nx;
    }
}

// ---------------------------------------------------------------------------
// Out-projection post-pass (verified R2/R3):
// out[b,t,o] = sum_n Out_w[o,n] * tanh(hidden[b,t,n])
// ---------------------------------------------------------------------------
__device__ __forceinline__ float half_wave_sum_(float x) {
    x += dpp_mov<0x111>(x);
    x += dpp_mov<0x112>(x);
    x += dpp_mov<0x114>(x);
    x += dpp_mov<0x118>(x);
    x += dpp_mov<0x142>(x);
    return x;
}
__device__ __forceinline__ float wave_sum_(float x) {
    x = half_wave_sum_(x);
    x += dpp_mov<0x143>(x);
    return x;
}

__global__ __launch_bounds__(256) void out_kernel(
    const float* __restrict__ hidden,  // [B,T,N]
    const float* __restrict__ Out_w,   // [OUTC,N]
    float* __restrict__ out)           // [B,T,OUTC]
{
    const int wv = (blockIdx.x << 2) | (threadIdx.x >> 6);
    const int p  = threadIdx.x & 63;
    const int NW = gridDim.x << 2;

    float Ow[OUTC][8];
    #pragma unroll
    for (int o = 0; o < OUTC; ++o) {
        float4 w0 = *(const float4*)&Out_w[o * NN + p * 4];
        float4 w1 = *(const float4*)&Out_w[o * NN + 256 + p * 4];
        Ow[o][0] = w0.x; Ow[o][1] = w0.y; Ow[o][2] = w0.z; Ow[o][3] = w0.w;
        Ow[o][4] = w1.x; Ow[o][5] = w1.y; Ow[o][6] = w1.z; Ow[o][7] = w1.w;
    }

    const int ROWS = BATCH * TT;
    for (int r = wv; r < ROWS; r += NW) {
        const float4* hp = (const float4*)(hidden + (size_t)r * NN);
        float4 a = hp[p];
        float4 c = hp[64 + p];
        float ph[8];
        ph[0] = fast_tanh(a.x); ph[1] = fast_tanh(a.y);
        ph[2] = fast_tanh(a.z); ph[3] = fast_tanh(a.w);
        ph[4] = fast_tanh(c.x); ph[5] = fast_tanh(c.y);
        ph[6] = fast_tanh(c.z); ph[7] = fast_tanh(c.w);
        #pragma unroll
        for (int o = 0; o < OUTC; ++o) {
            float sa = Ow[o][0] * ph[0];
            float sb = Ow[o][1] * ph[1];
            sa = fmaf(Ow[o][2], ph[2], sa);
            sb = fmaf(Ow[o][3], ph[3], sb);
            sa = fmaf(Ow[o][4], ph[4], sa);
            sb = fmaf(Ow[o][5], ph[5], sb);
            sa = fmaf(Ow[o][6], ph[6], sa);
            sb = fmaf(Ow[o][7], ph[7], sb);
            float s = sa + sb;
            s = wave_sum_(s);
            if (p == 63) out[(size_t)r * OUTC + o] = s;
        }
    }
}

extern "C" void kernel_launch(void* const* d_in, const int* in_sizes, int n_in,
                              void* d_out, int out_size, void* d_ws, size_t ws_size,
                              hipStream_t stream) {
    const float* x    = (const float*)d_in[0];  // [64,1024,16]
    const float* In_w = (const float*)d_in[1];  // [512,16]
    const float* V_w  = (const float*)d_in[2];  // [16,512]
    const float* U_w  = (const float*)d_in[3];  // [512,16]
    const float* Ow   = (const float*)d_in[4];  // [8,512]
    const float* h0   = (const float*)d_in[5];  // [512]

    float* hidden = (float*)d_out;                         // [64,1024,512]
    float* out    = hidden + (size_t)BATCH * TT * NN;      // [64,1024,8]
    float* Inp    = (float*)d_ws;                          // [64,1024,512]

    // 1) input projection (memory-bound)
    inp_kernel<<<1024, 256, 0, stream>>>(x, In_w, Inp);
    // 2) recurrent scan: 64 blocks x 256 thr, 1 batch/block, 1 barrier/step
    scan_kernel<<<BATCH, 256, 0, stream>>>(Inp, V_w, U_w, h0, hidden);
    // 3) out-projection from stored hidden (memory-bound)
    out_kernel<<<1024, 256, 0, stream>>>(hidden, Ow, out);
}